// Round 2
// baseline (113.760 us; speedup 1.0000x reference)
//
#include <hip/hip_runtime.h>
#include <hip/hip_bf16.h>

typedef short s8v __attribute__((ext_vector_type(8)));
typedef float f4v __attribute__((ext_vector_type(4)));
typedef unsigned short u16;
typedef unsigned int   u32;
typedef unsigned long long u64;

#define NHEAD 8
#define FDIM  32   // D/2

__device__ __forceinline__ float bf2f(u16 b) {
    return __uint_as_float(((u32)b) << 16);
}
__device__ __forceinline__ u16 f2bf(float f) {
    u32 u = __float_as_uint(f);
    u32 r = u + 0x7fffu + ((u >> 16) & 1u);   // round-to-nearest-even
    return (u16)(r >> 16);
}

// Per-wave dtype detection. ALL 64 lanes must be active when called.
// [isbf] floats are bf16; [mbyte] mask is byte-packed; [i64f] indices are int64.
__device__ __forceinline__ void detect_wave(const void* W1p, const void* maskp,
                                            const void* eidxp, int lane,
                                            int& isbf, int& mbyte, int& i64f) {
    u32 w1w = ((const u32*)W1p)[lane];
    u32 e = (w1w >> 7) & 0xFFu;                 // bf16 low-elem exponent byte if bf16
    u64 bE = __ballot(e >= 0x70u && e <= 0x7Fu);
    isbf = (__popcll(bE) > 32) ? 1 : 0;
    u32 mkw = ((const u32*)maskp)[lane];
    u64 bM = __ballot(mkw > 1u);                // packed bytes -> words > 1
    mbyte = (bM != 0ull) ? 1 : 0;
    u32 od = ((const u32*)eidxp)[2 * lane + 1];
    u64 bI = __ballot(od != 0u);                // int64 -> odd words all zero
    i64f = (bI == 0ull) ? 1 : 0;
}

// Pass A: zero agg + compact valid edge ids into list.
__global__ __launch_bounds__(256)
void compact_kernel(const void* __restrict__ eidx,
                    const void* __restrict__ maskp,
                    const int*  __restrict__ proP,
                    const void* __restrict__ W1p,
                    float* __restrict__ agg,
                    int*   __restrict__ cnt,
                    int*   __restrict__ list,
                    int E, int N3)
{
    const int lane = threadIdx.x & 63;
    int isbf, mbyte, i64f;
    detect_wave(W1p, maskp, eidx, lane, isbf, mbyte, i64f);
    (void)isbf;

    const int pro = proP[0];
    const int gid = blockIdx.x * blockDim.x + threadIdx.x;
    const int stride = gridDim.x * blockDim.x;

    for (int i = gid; i < N3; i += stride) agg[i] = 0.f;

    bool v = false;
    if (gid < E) {
        int src = i64f ? (int)((const long long*)eidx)[gid] : ((const int*)eidx)[gid];
        int mk  = mbyte ? (int)((const unsigned char*)maskp)[gid] : ((const int*)maskp)[gid];
        v = (src >= pro) && (mk == 0);
    }
    u64 bal = __ballot(v);
    int nv = __popcll(bal);
    int base = 0;
    if (lane == 0 && nv) base = atomicAdd(cnt, nv);
    base = __shfl(base, 0);
    if (v) {
        int off = __popcll(bal & ((1ull << lane) - 1ull));
        list[base + off] = gid;
    }
}

// Pass B: dense MFMA over compacted edges, 2 edges per wave-tile, grid-stride.
__global__ __launch_bounds__(256)
void attn_kernel(const void* __restrict__ a_ij,
                 const void* __restrict__ pos,
                 const void* __restrict__ eidx,
                 const void* __restrict__ maskp,
                 const void* __restrict__ W1p,
                 const void* __restrict__ b1p,
                 const void* __restrict__ W2p,
                 const void* __restrict__ b2p,
                 const void* __restrict__ Whp,
                 float* __restrict__ agg,
                 const int* __restrict__ cnt,
                 const int* __restrict__ list,
                 int E)
{
    const int lane = threadIdx.x & 63;
    int isbf, mbyte, i64f;
    detect_wave(W1p, maskp, eidx, lane, isbf, mbyte, i64f);
    (void)mbyte;

    const int c0 = lane & 15, c1 = c0 + 16;
    const int krow = (lane >> 4) * 8;
    const int row  = lane & 15;
    const int hi4  = (lane >> 4) & 1;

    // ---- per-wave parameter setup (verified layout from round 1) ----
    float sumWh = 0.f;
    float wh0, wh1, wh2, wh3;                 // hi4-selected Wh values
    float b1c0, b1c1, w2c0, w2c1, b2v;
    s8v bfrag[2][2];
    {
        float WhV[NHEAD];
        if (isbf) {
            const u16* w1 = (const u16*)W1p; const u16* b1 = (const u16*)b1p;
            const u16* w2 = (const u16*)W2p; const u16* b2 = (const u16*)b2p;
            const u16* wh = (const u16*)Whp;
            #pragma unroll
            for (int h = 0; h < NHEAD; ++h) { WhV[h] = bf2f(wh[h]); sumWh += WhV[h]; }
            b2v = bf2f(b2[0]);
            b1c0 = bf2f(b1[c0]); b1c1 = bf2f(b1[c1]);
            w2c0 = bf2f(w2[c0]); w2c1 = bf2f(w2[c1]);
            #pragma unroll
            for (int cb = 0; cb < 2; ++cb)
                #pragma unroll
                for (int kh = 0; kh < 2; ++kh)
                    #pragma unroll
                    for (int j = 0; j < 8; ++j) {
                        int k = kh * 32 + krow + j;
                        bfrag[cb][kh][j] = (short)w1[k * FDIM + cb * 16 + c0];
                    }
        } else {
            const float* w1 = (const float*)W1p; const float* b1 = (const float*)b1p;
            const float* w2 = (const float*)W2p; const float* b2 = (const float*)b2p;
            const float* wh = (const float*)Whp;
            #pragma unroll
            for (int h = 0; h < NHEAD; ++h) { WhV[h] = wh[h]; sumWh += WhV[h]; }
            b2v = b2[0];
            b1c0 = b1[c0]; b1c1 = b1[c1];
            w2c0 = w2[c0]; w2c1 = w2[c1];
            #pragma unroll
            for (int cb = 0; cb < 2; ++cb)
                #pragma unroll
                for (int kh = 0; kh < 2; ++kh)
                    #pragma unroll
                    for (int j = 0; j < 8; ++j) {
                        int k = kh * 32 + krow + j;
                        bfrag[cb][kh][j] = (short)f2bf(w1[k * FDIM + cb * 16 + c0]);
                    }
        }
        wh0 = hi4 ? WhV[4] : WhV[0];
        wh1 = hi4 ? WhV[5] : WhV[1];
        wh2 = hi4 ? WhV[6] : WhV[2];
        wh3 = hi4 ? WhV[7] : WhV[3];
    }

    const u16*   a16 = (const u16*)a_ij;
    const float* a32 = (const float*)a_ij;
    const int*   e32 = (const int*)eidx;
    const long long* e64 = (const long long*)eidx;

    const int count = cnt[0];
    const int ntv = (count + 1) >> 1;
    const int gw = blockIdx.x * (blockDim.x >> 6) + (threadIdx.x >> 6);
    const int nw = gridDim.x * (blockDim.x >> 6);

    for (int t = gw; t < ntv; t += nw) {
        const int i0 = 2 * t;
        const bool has1 = (i0 + 1) < count;
        const int eA = list[i0];
        const int eB = has1 ? list[i0 + 1] : eA;
        const int edge = (row < 8) ? eA : eB;
        const size_t rowbase = ((size_t)edge * 8 + (size_t)(row & 7)) * 64 + (size_t)krow;

        s8v a0, a1;
        if (isbf) {
            a0 = *(const s8v*)(a16 + rowbase);
            a1 = *(const s8v*)(a16 + rowbase + 32);
        } else {
            const float* p = a32 + rowbase;
            #pragma unroll
            for (int j = 0; j < 8; ++j) a0[j] = (short)f2bf(p[j]);
            #pragma unroll
            for (int j = 0; j < 8; ++j) a1[j] = (short)f2bf(p[32 + j]);
        }

        f4v C0 = {0.f,0.f,0.f,0.f}, C1 = {0.f,0.f,0.f,0.f};
        C0 = __builtin_amdgcn_mfma_f32_16x16x32_bf16(a0, bfrag[0][0], C0, 0, 0, 0);
        C0 = __builtin_amdgcn_mfma_f32_16x16x32_bf16(a1, bfrag[0][1], C0, 0, 0, 0);
        C1 = __builtin_amdgcn_mfma_f32_16x16x32_bf16(a0, bfrag[1][0], C1, 0, 0, 0);
        C1 = __builtin_amdgcn_mfma_f32_16x16x32_bf16(a1, bfrag[1][1], C1, 0, 0, 0);

        float partial;
        {
            float x0, x1, trow;
            x0 = C0[0] + b1c0; x0 = (x0 >= 0.f) ? x0 : 0.01f * x0;
            x1 = C1[0] + b1c1; x1 = (x1 >= 0.f) ? x1 : 0.01f * x1;
            trow = x0 * w2c0 + x1 * w2c1; partial  = trow * wh0;
            x0 = C0[1] + b1c0; x0 = (x0 >= 0.f) ? x0 : 0.01f * x0;
            x1 = C1[1] + b1c1; x1 = (x1 >= 0.f) ? x1 : 0.01f * x1;
            trow = x0 * w2c0 + x1 * w2c1; partial += trow * wh1;
            x0 = C0[2] + b1c0; x0 = (x0 >= 0.f) ? x0 : 0.01f * x0;
            x1 = C1[2] + b1c1; x1 = (x1 >= 0.f) ? x1 : 0.01f * x1;
            trow = x0 * w2c0 + x1 * w2c1; partial += trow * wh2;
            x0 = C0[3] + b1c0; x0 = (x0 >= 0.f) ? x0 : 0.01f * x0;
            x1 = C1[3] + b1c1; x1 = (x1 >= 0.f) ? x1 : 0.01f * x1;
            trow = x0 * w2c0 + x1 * w2c1; partial += trow * wh3;
        }
        partial += __shfl_xor(partial, 1);
        partial += __shfl_xor(partial, 2);
        partial += __shfl_xor(partial, 4);
        partial += __shfl_xor(partial, 8);
        partial += __shfl_xor(partial, 16);
        const float att = partial + b2v * sumWh;

        if ((lane & 31) == 0) {
            const int which = lane >> 5;
            if (!which || has1) {
                const int e = which ? eB : eA;
                const int s = i64f ? (int)e64[e]     : e32[e];
                const int d = i64f ? (int)e64[E + e] : e32[E + e];
                float px, py, pz, qx, qy, qz;
                if (isbf) {
                    const u16* pp = (const u16*)pos;
                    px = bf2f(pp[3 * s]); py = bf2f(pp[3 * s + 1]); pz = bf2f(pp[3 * s + 2]);
                    qx = bf2f(pp[3 * d]); qy = bf2f(pp[3 * d + 1]); qz = bf2f(pp[3 * d + 2]);
                } else {
                    const float* pp = (const float*)pos;
                    px = pp[3 * s]; py = pp[3 * s + 1]; pz = pp[3 * s + 2];
                    qx = pp[3 * d]; qy = pp[3 * d + 1]; qz = pp[3 * d + 2];
                }
                float dx = px - qx, dy = py - qy, dz = pz - qz;
                float nrm = sqrtf(dx * dx + dy * dy + dz * dz) + 1e-6f;
                float sc = att / nrm;
                atomicAdd(&agg[3 * s + 0], dx * sc);
                atomicAdd(&agg[3 * s + 1], dy * sc);
                atomicAdd(&agg[3 * s + 2], dz * sc);
            }
        }
    }
}

__global__ __launch_bounds__(256)
void finalize_kernel(const void* __restrict__ pos,
                     const void* __restrict__ gidxp,
                     const float* __restrict__ agg,
                     void* __restrict__ outp,
                     const void* __restrict__ W1p,
                     const void* __restrict__ maskp,
                     const void* __restrict__ eidxp,
                     int G)
{
    const int lane = threadIdx.x & 63;
    int isbf, mbyte, i64f;
    detect_wave(W1p, maskp, eidxp, lane, isbf, mbyte, i64f);
    (void)mbyte;

    int g = blockIdx.x * blockDim.x + threadIdx.x;
    if (g >= G) return;
    const int idx = i64f ? (int)((const long long*)gidxp)[g] : ((const int*)gidxp)[g];
    #pragma unroll
    for (int c = 0; c < 3; ++c) {
        float p;
        if (isbf) p = bf2f(((const u16*)pos)[3 * idx + c]);
        else      p = ((const float*)pos)[3 * idx + c];
        float v = p + agg[3 * idx + c];
        if (isbf) ((u16*)outp)[3 * g + c] = f2bf(v);
        else      ((float*)outp)[3 * g + c] = v;
    }
}

extern "C" void kernel_launch(void* const* d_in, const int* in_sizes, int n_in,
                              void* d_out, int out_size, void* d_ws, size_t ws_size,
                              hipStream_t stream) {
    const void* a_ij = d_in[0];
    const void* pos  = d_in[1];
    const void* eidx = d_in[3];
    const void* gidx = d_in[5];
    const void* mask = d_in[6];
    const int*  pro  = (const int*)d_in[7];
    const void* W1   = d_in[8];
    const void* b1   = d_in[9];
    const void* W2   = d_in[10];
    const void* b2   = d_in[11];
    const void* Wh   = d_in[12];

    const int E = in_sizes[3] / 2;
    const int N = in_sizes[1] / 3;
    const int G = in_sizes[5];
    const int N3 = N * 3;

    const size_t aggBytes = (size_t)N3 * sizeof(float);
    float* agg  = (float*)d_ws;
    char*  p    = (char*)d_ws + ((aggBytes + 255) & ~(size_t)255);
    int*   cnt  = (int*)p;                   // 64 B
    int*   list = (int*)(p + 64);            // E ints worst case

    hipMemsetAsync(cnt, 0, 64, stream);

    const int blocksA = (E + 255) / 256;
    compact_kernel<<<blocksA, 256, 0, stream>>>(eidx, mask, pro, W1, agg, cnt, list, E, N3);

    attn_kernel<<<2048, 256, 0, stream>>>(a_ij, pos, eidx, mask, W1, b1, W2, b2, Wh,
                                          agg, cnt, list, E);

    finalize_kernel<<<(G + 255) / 256, 256, 0, stream>>>(pos, gidx, agg, d_out,
                                                         W1, mask, eidx, G);
}